// Round 22
// baseline (70.296 us; speedup 1.0000x reference)
//
#include <hip/hip_runtime.h>
#include <hip/hip_bf16.h>

#define BB 2
#define TT 1024
#define DD 512
#define HH 8
#define FF 16
#define HDIM 64
#define BT (BB*TT)   // 2048

typedef short bf16x8 __attribute__((ext_vector_type(8)));
typedef float f32x4  __attribute__((ext_vector_type(4)));
#define MFMA_BF16 __builtin_amdgcn_mfma_f32_16x16x32_bf16

// float -> bf16 round-to-nearest-even (scalar)
__device__ __forceinline__ ushort f2b(float f) {
    uint u = __float_as_uint(f);
    uint r = (u + 0x7fffu + ((u >> 16) & 1u)) >> 16;
    return (ushort)r;
}

// pack two floats -> one dword of 2 bf16
__device__ __forceinline__ uint pkbf2(float a, float b) {
    __hip_bfloat162 h = __float22bfloat162_rn(make_float2(a, b));
    union { __hip_bfloat162 h2; uint u; } c; c.h2 = h;
    return c.u;
}

// ---------------------------------------------------------------------------
// Kernel 0: cast inputs to bf16 (round-21 body, rep-wrapped diagnostic).
// ---------------------------------------------------------------------------
__global__ __launch_bounds__(256) void cast_all(
    const float* __restrict__ X,  const float* __restrict__ Wq,
    const float* __restrict__ Wk, const float* __restrict__ Wv,
    const float* __restrict__ Wo,
    ushort* __restrict__ Xb, ushort* __restrict__ Wb, ushort* __restrict__ Wob,
    int rep)
{
    const int i4 = (blockIdx.x * 256 + threadIdx.x) * 4;
    const float* src; ushort* dst;
    if (i4 < 1048576)      { src = X  + i4;             dst = Xb + i4; }
    else if (i4 < 1114112) { src = Wq + (i4 - 1048576); dst = Wb + (i4 - 1048576); }
    else if (i4 < 1179648) { src = Wk + (i4 - 1114112); dst = Wb + 65536 + (i4 - 1114112); }
    else if (i4 < 1441792) { src = Wv + (i4 - 1179648); dst = Wb + 131072 + (i4 - 1179648); }
    else                   { src = Wo + (i4 - 1441792); dst = Wob + (i4 - 1441792); }
    for (int it = 0; it < rep; ++it) {
        float4 v = *(const float4*)src;
        ushort4 o = { f2b(v.x), f2b(v.y), f2b(v.z), f2b(v.w) };
        *(ushort4*)dst = o;
        asm volatile("" ::: "memory");
    }
}

// ---------------------------------------------------------------------------
// Kernel 1: QKV projection (round-21 body: 8-wave K-split, coalesced
// epilogue, K pre-scaled 1/4), rep-wrapped diagnostic.
// ---------------------------------------------------------------------------
__global__ __launch_bounds__(512) void qkv_mfma(
    const ushort* __restrict__ Xb, const ushort* __restrict__ Wb,
    ushort* __restrict__ Qb, ushort* __restrict__ Kb, ushort* __restrict__ Vtg,
    int rep)
{
    __shared__ float sc[2][64][66];
    const int m0 = blockIdx.x * 64, n0 = blockIdx.y * 64;
    const int tid = threadIdx.x, w = tid >> 6, l = tid & 63;
    const int kw = w >> 2, mw = w & 1, nw = (w >> 1) & 1;
    const int lr = l & 15, g = l >> 4;

    const ushort* Ar = Xb + (size_t)(m0 + mw*32 + lr) * 512 + kw*256 + g*8;
    const ushort* Br = Wb + (size_t)(n0 + nw*32 + lr) * 512 + kw*256 + g*8;

    for (int it = 0; it < rep; ++it) {
        __syncthreads();   // guard LDS reuse across reps

        f32x4 acc[2][2] = {};
        bf16x8 a0c = *(const bf16x8*)(Ar);
        bf16x8 a1c = *(const bf16x8*)(Ar + (size_t)16*512);
        bf16x8 b0c = *(const bf16x8*)(Br);
        bf16x8 b1c = *(const bf16x8*)(Br + (size_t)16*512);
        #pragma unroll
        for (int ks = 0; ks < 8; ++ks) {
            bf16x8 a0n = a0c, a1n = a1c, b0n = b0c, b1n = b1c;
            if (ks < 7) {
                a0n = *(const bf16x8*)(Ar + (ks+1)*32);
                a1n = *(const bf16x8*)(Ar + (size_t)16*512 + (ks+1)*32);
                b0n = *(const bf16x8*)(Br + (ks+1)*32);
                b1n = *(const bf16x8*)(Br + (size_t)16*512 + (ks+1)*32);
            }
            acc[0][0] = MFMA_BF16(a0c, b0c, acc[0][0], 0, 0, 0);
            acc[0][1] = MFMA_BF16(a0c, b1c, acc[0][1], 0, 0, 0);
            acc[1][0] = MFMA_BF16(a1c, b0c, acc[1][0], 0, 0, 0);
            acc[1][1] = MFMA_BF16(a1c, b1c, acc[1][1], 0, 0, 0);
            a0c = a0n; a1c = a1n; b0c = b0n; b1c = b1n;
        }

        #pragma unroll
        for (int mb = 0; mb < 2; ++mb)
            #pragma unroll
            for (int nb = 0; nb < 2; ++nb)
                #pragma unroll
                for (int r = 0; r < 4; ++r)
                    sc[kw][mw*32 + mb*16 + g*4 + r][nw*32 + nb*16 + lr] = acc[mb][nb][r];
        __syncthreads();

        if (n0 < 256) {
            const int hq   = tid >> 7;           // 0..3 head-group in tile
            const int r    = tid & 127;
            const int m    = r >> 1;             // 0..63 local token
            const int half = r & 1;              // 0/1: features half*8..+8
            const int c0 = n0 + hq*16;
            const bool isQ = c0 < 128;
            const int c = isQ ? c0 : c0 - 128;
            const int h = c >> 4;
            ushort* Dst = isQ ? Qb : Kb;
            const float scale = isQ ? 1.0f : 0.25f;   // K pre-scaled 1/4
            const int tok0 = m0 + m;
            const int b = tok0 >> 10, tt = tok0 & 1023;
            const int cb = hq*16 + half*8;
            ushort us[8];
            #pragma unroll
            for (int j = 0; j < 8; ++j)
                us[j] = f2b((sc[0][m][cb + j] + sc[1][m][cb + j]) * scale);
            *(uint4*)&Dst[((size_t)(b*HH + h)*TT + tt)*FF + half*8] = *(uint4*)us;
        } else {
            const int h   = (n0 - 256) >> 6;
            const int row = tid >> 3;            // 0..63 vch
            const int tc  = tid & 7;             // tokens tc*8..+8
            const int tok0 = m0 + tc*8;
            const int b = tok0 >> 10, tt0 = tok0 & 1023;
            ushort us[8];
            #pragma unroll
            for (int j = 0; j < 8; ++j)
                us[j] = f2b(sc[0][tc*8 + j][row] + sc[1][tc*8 + j][row]);
            *(uint4*)&Vtg[((size_t)(b*HH + h)*64 + row)*TT + tt0] = *(uint4*)us;
        }
        asm volatile("" ::: "memory");
    }
}

// ---------------------------------------------------------------------------
// Kernel 2: causal Taylor attention (round-21 body, UNREPPED — measured 8-9us
// in round 12; kept small so it doesn't crowd the top-5).
// ---------------------------------------------------------------------------
__global__ __launch_bounds__(512) void attn_mfma(
    const ushort* __restrict__ Qb, const ushort* __restrict__ Kb,
    const ushort* __restrict__ Vtg, ushort* __restrict__ Yb)
{
    __shared__ float smem[8*32*68 + 8*32];           // 70656 B
    short (*Pl)[32][72] = (short(*)[32][72])smem;    // [wave][q32][k64+8]
    float* scf = smem;                               // epi: [8][32][68]
    float* scd = smem + 8*32*68;                     // epi: [8][32]

    const int bid = blockIdx.x;
    const int qt = 31 - (bid >> 4);       // heavy q-tiles dispatch first (LPT)
    const int bh = bid & 15;
    const int b = bh >> 3, h = bh & 7;
    const int tid = threadIdx.x, w = tid >> 6, l = tid & 63;
    const int lr = l & 15, g = l >> 4;
    const int qend = qt*32 + 32;
    const int nkc = (qt + 2) >> 1;        // ceil(qend/64)
    const bf16x8 zf = {0,0,0,0,0,0,0,0};
    const bf16x8 ones = {16256,16256,16256,16256,16256,16256,16256,16256}; // bf16 1.0

    bf16x8 qf[2];
    #pragma unroll
    for (int nb = 0; nb < 2; ++nb)
        qf[nb] = (l < 32)
            ? *(const bf16x8*)(Qb + ((size_t)bh*TT + qt*32 + nb*16 + lr)*FF + g*8)
            : zf;

    f32x4 o[4][2] = {};       // o[mv][nb]: O^T partial over this wave's kc set
    f32x4 dacc[2] = {};       // den[q=lr] per nb (replicated across regs)

    for (int kc = w; kc < nkc; kc += 8) {
        const bool diagc = (kc == nkc - 1);           // wave-uniform
        const int act = qend - kc*64;
        const int nmb = diagc ? (act >> 4) : 4;       // 2 or 4 (always even)
        const int kb_max = nmb >> 1;                  // 1 or 2

        for (int mb = 0; mb < nmb; ++mb) {
            bf16x8 kf = (l < 32)
                ? *(const bf16x8*)(Kb + ((size_t)bh*TT + kc*64 + mb*16 + lr)*FF + g*8)
                : zf;
            #pragma unroll
            for (int nb = 0; nb < 2; ++nb) {
                f32x4 z4 = {};
                f32x4 s = MFMA_BF16(kf, qf[nb], z4, 0, 0, 0);  // s pre-scaled
                float pv[4];
                if (diagc) {
                    const int qg = qt*32 + nb*16 + lr;
                    const int kg0 = kc*64 + mb*16 + g*4;
                    #pragma unroll
                    for (int r = 0; r < 4; ++r) {
                        float pp = fmaf(s[r], fmaf(s[r], 0.5f, 1.0f), 1.0f);
                        pv[r] = (kg0 + r > qg) ? 0.f : pp;
                    }
                } else {
                    #pragma unroll
                    for (int r = 0; r < 4; ++r)
                        pv[r] = fmaf(s[r], fmaf(s[r], 0.5f, 1.0f), 1.0f);
                }
                uint2 pk = { pkbf2(pv[0], pv[1]), pkbf2(pv[2], pv[3]) };
                *(uint2*)&Pl[w][nb*16 + lr][mb*16 + g*4] = pk;
            }
        }

        for (int kb = 0; kb < kb_max; ++kb) {
            #pragma unroll
            for (int mv = 0; mv < 4; ++mv) {
                bf16x8 vf = *(const bf16x8*)(Vtg +
                    ((size_t)bh*64 + mv*16 + lr)*TT + kc*64 + kb*32 + g*8);
                #pragma unroll
                for (int nb = 0; nb < 2; ++nb) {
                    bf16x8 pf = *(const bf16x8*)&Pl[w][nb*16 + lr][kb*32 + g*8];
                    o[mv][nb] = MFMA_BF16(vf, pf, o[mv][nb], 0, 0, 0);
                }
            }
            #pragma unroll
            for (int nb = 0; nb < 2; ++nb) {
                bf16x8 pf = *(const bf16x8*)&Pl[w][nb*16 + lr][kb*32 + g*8];
                dacc[nb] = MFMA_BF16(ones, pf, dacc[nb], 0, 0, 0);
            }
        }
    }

    __syncthreads();   // all waves done with Pl (scratch overlays it)

    #pragma unroll
    for (int mv = 0; mv < 4; ++mv)
        #pragma unroll
        for (int nb = 0; nb < 2; ++nb)
            *(f32x4*)&scf[(size_t)(w*32 + nb*16 + lr)*68 + mv*16 + g*4] = o[mv][nb];
    if (g == 0) {
        scd[w*32 + lr]      = dacc[0][0];
        scd[w*32 + 16 + lr] = dacc[1][0];
    }

    __syncthreads();

    {
        const int q  = tid >> 4;           // 0..31
        const int v0 = (tid & 15) * 4;     // 0..60
        float dtot = 0.f;
        #pragma unroll
        for (int ww = 0; ww < 8; ++ww) dtot += scd[ww*32 + q];
        const float inv = 1.0f / (dtot + 1e-12f);
        float o0 = 0.f, o1 = 0.f, o2 = 0.f, o3 = 0.f;
        #pragma unroll
        for (int ww = 0; ww < 8; ++ww) {
            const float* p = &scf[(size_t)(ww*32 + q)*68 + v0];
            o0 += p[0]; o1 += p[1]; o2 += p[2]; o3 += p[3];
        }
        uint2 pk = { pkbf2(o0*inv, o1*inv), pkbf2(o2*inv, o3*inv) };
        *(uint2*)(Yb + ((size_t)(b*TT + qt*32 + q))*DD + h*HDIM + v0) = pk;
    }
}

// ---------------------------------------------------------------------------
// Kernel 3: output projection (round-21 body), rep-wrapped diagnostic.
// ---------------------------------------------------------------------------
__global__ __launch_bounds__(512) void out_mfma(
    const ushort* __restrict__ Yb, const ushort* __restrict__ Wob,
    float* __restrict__ Out, int rep)
{
    __shared__ float sc[2][64][66];
    const int m0 = blockIdx.x * 64, n0 = blockIdx.y * 64;
    const int tid = threadIdx.x, w = tid >> 6, l = tid & 63;
    const int kw = w >> 2, mw = w & 1, nw = (w >> 1) & 1;
    const int lr = l & 15, g = l >> 4;

    const ushort* Ar = Yb  + (size_t)(m0 + mw*32 + lr) * 512 + kw*256 + g*8;
    const ushort* Br = Wob + (size_t)(n0 + nw*32 + lr) * 512 + kw*256 + g*8;

    for (int it = 0; it < rep; ++it) {
        __syncthreads();   // guard LDS reuse across reps

        f32x4 acc[2][2] = {};
        bf16x8 a0c = *(const bf16x8*)(Ar);
        bf16x8 a1c = *(const bf16x8*)(Ar + (size_t)16*512);
        bf16x8 b0c = *(const bf16x8*)(Br);
        bf16x8 b1c = *(const bf16x8*)(Br + (size_t)16*512);
        #pragma unroll
        for (int ks = 0; ks < 8; ++ks) {
            bf16x8 a0n = a0c, a1n = a1c, b0n = b0c, b1n = b1c;
            if (ks < 7) {
                a0n = *(const bf16x8*)(Ar + (ks+1)*32);
                a1n = *(const bf16x8*)(Ar + (size_t)16*512 + (ks+1)*32);
                b0n = *(const bf16x8*)(Br + (ks+1)*32);
                b1n = *(const bf16x8*)(Br + (size_t)16*512 + (ks+1)*32);
            }
            acc[0][0] = MFMA_BF16(a0c, b0c, acc[0][0], 0, 0, 0);
            acc[0][1] = MFMA_BF16(a0c, b1c, acc[0][1], 0, 0, 0);
            acc[1][0] = MFMA_BF16(a1c, b0c, acc[1][0], 0, 0, 0);
            acc[1][1] = MFMA_BF16(a1c, b1c, acc[1][1], 0, 0, 0);
            a0c = a0n; a1c = a1n; b0c = b0n; b1c = b1n;
        }

        #pragma unroll
        for (int mb = 0; mb < 2; ++mb)
            #pragma unroll
            for (int nb = 0; nb < 2; ++nb)
                #pragma unroll
                for (int r = 0; r < 4; ++r)
                    sc[kw][mw*32 + mb*16 + g*4 + r][nw*32 + nb*16 + lr] = acc[mb][nb][r];
        __syncthreads();

        const int vl = tid & 63, rg = tid >> 6;
        #pragma unroll
        for (int j = 0; j < 8; ++j) {
            const float v = sc[0][rg*8 + j][vl] + sc[1][rg*8 + j][vl];
            Out[(size_t)(m0 + rg*8 + j)*512 + n0 + vl] = v;
        }
        asm volatile("" ::: "memory");
    }
}

// ---------------------------------------------------------------------------
extern "C" void kernel_launch(void* const* d_in, const int* in_sizes, int n_in,
                              void* d_out, int out_size, void* d_ws, size_t ws_size,
                              hipStream_t stream) {
    const float* X  = (const float*)d_in[0];   // (2,1024,512)
    const float* Wq = (const float*)d_in[1];   // (128,512)
    const float* Wk = (const float*)d_in[2];   // (128,512)
    const float* Wv = (const float*)d_in[3];   // (512,512)
    const float* Wo = (const float*)d_in[4];   // (512,512)
    float* out = (float*)d_out;                // (2,1024,512)

    ushort* ws = (ushort*)d_ws;
    ushort* Xb  = ws;                    // 2048*512   = 1048576
    ushort* Wb  = Xb  + 1048576;         // 768*512    = 393216
    ushort* Wob = Wb  + 393216;          // 512*512    = 262144
    ushort* Qb  = Wob + 262144;          // 16*1024*16 = 262144
    ushort* Kb  = Qb  + 262144;          // 262144
    ushort* Vtg = Kb  + 262144;          // 16*64*1024 = 1048576
    ushort* Yb  = Vtg + 1048576;         // 2048*512   = 1048576

    // DIAGNOSTIC ROUND 3: rep factors surface cast/qkv/out in rocprof top-5
    // (attn already measured at 8-9us in round 12). Ledger next round decides:
    // plateau-and-settle vs attack the dominant kernel.
    const int REP_CAST = 12, REP_QKV = 8, REP_OUT = 8;

    cast_all<<<1664, 256, 0, stream>>>(X, Wq, Wk, Wv, Wo, Xb, Wb, Wob, REP_CAST);

    dim3 g1(BT/64, 768/64);   // 32 x 12 = 384 blocks, 512 thr
    qkv_mfma<<<g1, 512, 0, stream>>>(Xb, Wb, Qb, Kb, Vtg, REP_QKV);

    attn_mfma<<<512, 512, 0, stream>>>(Qb, Kb, Vtg, Yb);

    dim3 g3(BT/64, DD/64);    // 32 x 8 = 256 blocks, 512 thr
    out_mfma<<<g3, 512, 0, stream>>>(Yb, Wob, out, REP_OUT);
}

// Round 23
// 43.113 us; speedup vs baseline: 1.6305x; 1.6305x over previous
//
#include <hip/hip_runtime.h>
#include <hip/hip_bf16.h>

#define BB 2
#define TT 1024
#define DD 512
#define HH 8
#define FF 16
#define HDIM 64
#define BT (BB*TT)   // 2048

typedef short bf16x8 __attribute__((ext_vector_type(8)));
typedef float f32x4  __attribute__((ext_vector_type(4)));
#define MFMA_BF16 __builtin_amdgcn_mfma_f32_16x16x32_bf16

// float -> bf16 round-to-nearest-even (scalar)
__device__ __forceinline__ ushort f2b(float f) {
    uint u = __float_as_uint(f);
    uint r = (u + 0x7fffu + ((u >> 16) & 1u)) >> 16;
    return (ushort)r;
}

// pack two floats -> one dword of 2 bf16
__device__ __forceinline__ uint pkbf2(float a, float b) {
    __hip_bfloat162 h = __float22bfloat162_rn(make_float2(a, b));
    union { __hip_bfloat162 h2; uint u; } c; c.h2 = h;
    return c.u;
}

// ---------------------------------------------------------------------------
// Kernel 1: FUSED cast + QKV projection (kills the cast dispatch).
// Grid (16, 7): by 0..5 = 128x128 GEMM tiles (by0=Q, by1=K, by2-5=V);
// by==6 = Wo->bf16 cast tail (16 blocks).
// Per block: K processed in 4 chunks of 128; each chunk's X/W f32 panels are
// loaded ONCE (coalesced float4, 1KB/wave/instr), converted to bf16 into LDS,
// and MFMA fragments read from LDS. f32 global traffic = 48MB total (X 6x,
// W 16x) == the old bf16 path's L2 traffic; no per-fragment re-reads (the
// r10/11 mistake). 8 waves = 4m x 2n, wave tile 32x64, full K=512, acc[2][4].
// Epilogue routes Q,K (K pre-scaled 1/4) -> (bh,t,16); V -> Vt[bh][64][1024].
// Numerics identical to cast_all+qkv (same RNE conversions).
// ---------------------------------------------------------------------------
__global__ __launch_bounds__(512) void qkv_f32(
    const float* __restrict__ X,  const float* __restrict__ Wq,
    const float* __restrict__ Wk, const float* __restrict__ Wv,
    const float* __restrict__ Wo,
    ushort* __restrict__ Qb, ushort* __restrict__ Kb,
    ushort* __restrict__ Vtg, ushort* __restrict__ Wob)
{
    if (blockIdx.y == 6) {   // Wo cast tail: 16 blocks x 512 thr x 8 float4
        const int idx = blockIdx.x * 512 + threadIdx.x;   // 0..8191
        #pragma unroll
        for (int j = 0; j < 8; ++j) {
            const int u = j * 8192 + idx;                 // 0..65535 float4s
            float4 v = *(const float4*)(Wo + (size_t)u * 4);
            ushort4 o = { f2b(v.x), f2b(v.y), f2b(v.z), f2b(v.w) };
            *(ushort4*)(Wob + (size_t)u * 4) = o;
        }
        return;
    }

    __shared__ short LA[128][136];   // 34.8KB, +8 pad
    __shared__ short LB[128][136];   // 34.8KB

    const int m0 = blockIdx.x * 128;
    const int by = blockIdx.y;
    const int tid = threadIdx.x, w = tid >> 6, l = tid & 63;
    const int mw = w & 3, nw = w >> 2;      // 4 m-waves x 2 n-waves
    const int lr = l & 15, g = l >> 4;

    const float* Wsrc = (by == 0) ? Wq
                      : (by == 1) ? Wk
                      : (Wv + (size_t)(by - 2) * 128 * 512);

    f32x4 acc[2][4] = {};

    for (int kc = 0; kc < 4; ++kc) {
        __syncthreads();   // previous chunk's fragment reads done
        // stage 128x128 f32 chunks of X and Wsrc -> bf16 LDS (coalesced)
        #pragma unroll
        for (int i = 0; i < 8; ++i) {
            const int f = i * 512 + tid;          // float4 idx 0..4095
            const int row = f >> 5, c4 = f & 31;  // 32 float4 per row
            float4 va = *(const float4*)(X + (size_t)(m0 + row) * 512 + kc*128 + c4*4);
            uint2 pa = { pkbf2(va.x, va.y), pkbf2(va.z, va.w) };
            *(uint2*)&LA[row][c4*4] = pa;
            float4 vb = *(const float4*)(Wsrc + (size_t)row * 512 + kc*128 + c4*4);
            uint2 pb = { pkbf2(vb.x, vb.y), pkbf2(vb.z, vb.w) };
            *(uint2*)&LB[row][c4*4] = pb;
        }
        __syncthreads();

        #pragma unroll
        for (int ks = 0; ks < 4; ++ks) {
            bf16x8 a0 = *(const bf16x8*)&LA[mw*32      + lr][ks*32 + g*8];
            bf16x8 a1 = *(const bf16x8*)&LA[mw*32 + 16 + lr][ks*32 + g*8];
            bf16x8 b0 = *(const bf16x8*)&LB[nw*64      + lr][ks*32 + g*8];
            bf16x8 b1 = *(const bf16x8*)&LB[nw*64 + 16 + lr][ks*32 + g*8];
            bf16x8 b2 = *(const bf16x8*)&LB[nw*64 + 32 + lr][ks*32 + g*8];
            bf16x8 b3 = *(const bf16x8*)&LB[nw*64 + 48 + lr][ks*32 + g*8];
            acc[0][0] = MFMA_BF16(a0, b0, acc[0][0], 0, 0, 0);
            acc[0][1] = MFMA_BF16(a0, b1, acc[0][1], 0, 0, 0);
            acc[0][2] = MFMA_BF16(a0, b2, acc[0][2], 0, 0, 0);
            acc[0][3] = MFMA_BF16(a0, b3, acc[0][3], 0, 0, 0);
            acc[1][0] = MFMA_BF16(a1, b0, acc[1][0], 0, 0, 0);
            acc[1][1] = MFMA_BF16(a1, b1, acc[1][1], 0, 0, 0);
            acc[1][2] = MFMA_BF16(a1, b2, acc[1][2], 0, 0, 0);
            acc[1][3] = MFMA_BF16(a1, b3, acc[1][3], 0, 0, 0);
        }
    }

    if (by < 2) {
        // Q (by==0) or K (by==1): features 0..127 -> h = n>>4, f = n&15
        ushort* Dst = (by == 0) ? Qb : Kb;
        const float scale = (by == 0) ? 1.0f : 0.25f;   // K pre-scaled 1/4
        #pragma unroll
        for (int mb = 0; mb < 2; ++mb)
            #pragma unroll
            for (int nb = 0; nb < 4; ++nb) {
                const int n = nw*64 + nb*16 + lr;
                const int h = n >> 4, fc = n & 15;
                #pragma unroll
                for (int r = 0; r < 4; ++r) {
                    const int tok = m0 + mw*32 + mb*16 + g*4 + r;
                    const int b = tok >> 10, tt = tok & 1023;
                    Dst[((size_t)(b*HH + h)*TT + tt)*FF + fc] =
                        f2b(acc[mb][nb][r] * scale);
                }
            }
    } else {
        // V: features (by-2)*128 + .. in 0..511 -> h = n>>6, v = n&63
        #pragma unroll
        for (int mb = 0; mb < 2; ++mb)
            #pragma unroll
            for (int nb = 0; nb < 4; ++nb) {
                const int n = (by - 2)*128 + nw*64 + nb*16 + lr;
                const int h = n >> 6, v = n & 63;
                const int tok0 = m0 + mw*32 + mb*16 + g*4;
                const int b = tok0 >> 10, tt0 = tok0 & 1023;
                uint2 pk = { pkbf2(acc[mb][nb][0], acc[mb][nb][1]),
                             pkbf2(acc[mb][nb][2], acc[mb][nb][3]) };
                *(uint2*)&Vtg[((size_t)(b*HH + h)*64 + v)*TT + tt0] = pk;
            }
    }
}

// ---------------------------------------------------------------------------
// Kernel 2: causal Taylor attention, bf16 MFMA, 8-wave split-K (round-21
// body, unchanged): 32 q-rows/block, 512 blocks, VALU diet + den-MFMA.
// ---------------------------------------------------------------------------
__global__ __launch_bounds__(512) void attn_mfma(
    const ushort* __restrict__ Qb, const ushort* __restrict__ Kb,
    const ushort* __restrict__ Vtg, ushort* __restrict__ Yb)
{
    __shared__ float smem[8*32*68 + 8*32];           // 70656 B
    short (*Pl)[32][72] = (short(*)[32][72])smem;    // [wave][q32][k64+8]
    float* scf = smem;                               // epi: [8][32][68]
    float* scd = smem + 8*32*68;                     // epi: [8][32]

    const int bid = blockIdx.x;
    const int qt = 31 - (bid >> 4);       // heavy q-tiles dispatch first (LPT)
    const int bh = bid & 15;
    const int b = bh >> 3, h = bh & 7;
    const int tid = threadIdx.x, w = tid >> 6, l = tid & 63;
    const int lr = l & 15, g = l >> 4;
    const int qend = qt*32 + 32;
    const int nkc = (qt + 2) >> 1;        // ceil(qend/64)
    const bf16x8 zf = {0,0,0,0,0,0,0,0};
    const bf16x8 ones = {16256,16256,16256,16256,16256,16256,16256,16256}; // bf16 1.0

    bf16x8 qf[2];
    #pragma unroll
    for (int nb = 0; nb < 2; ++nb)
        qf[nb] = (l < 32)
            ? *(const bf16x8*)(Qb + ((size_t)bh*TT + qt*32 + nb*16 + lr)*FF + g*8)
            : zf;

    f32x4 o[4][2] = {};       // o[mv][nb]: O^T partial over this wave's kc set
    f32x4 dacc[2] = {};       // den[q=lr] per nb (replicated across regs)

    for (int kc = w; kc < nkc; kc += 8) {
        const bool diagc = (kc == nkc - 1);           // wave-uniform
        const int act = qend - kc*64;
        const int nmb = diagc ? (act >> 4) : 4;       // 2 or 4 (always even)
        const int kb_max = nmb >> 1;                  // 1 or 2

        for (int mb = 0; mb < nmb; ++mb) {
            bf16x8 kf = (l < 32)
                ? *(const bf16x8*)(Kb + ((size_t)bh*TT + kc*64 + mb*16 + lr)*FF + g*8)
                : zf;
            #pragma unroll
            for (int nb = 0; nb < 2; ++nb) {
                f32x4 z4 = {};
                f32x4 s = MFMA_BF16(kf, qf[nb], z4, 0, 0, 0);  // s pre-scaled
                float pv[4];
                if (diagc) {
                    const int qg = qt*32 + nb*16 + lr;
                    const int kg0 = kc*64 + mb*16 + g*4;
                    #pragma unroll
                    for (int r = 0; r < 4; ++r) {
                        float pp = fmaf(s[r], fmaf(s[r], 0.5f, 1.0f), 1.0f);
                        pv[r] = (kg0 + r > qg) ? 0.f : pp;
                    }
                } else {
                    #pragma unroll
                    for (int r = 0; r < 4; ++r)
                        pv[r] = fmaf(s[r], fmaf(s[r], 0.5f, 1.0f), 1.0f);
                }
                uint2 pk = { pkbf2(pv[0], pv[1]), pkbf2(pv[2], pv[3]) };
                *(uint2*)&Pl[w][nb*16 + lr][mb*16 + g*4] = pk;
            }
        }

        for (int kb = 0; kb < kb_max; ++kb) {
            #pragma unroll
            for (int mv = 0; mv < 4; ++mv) {
                bf16x8 vf = *(const bf16x8*)(Vtg +
                    ((size_t)bh*64 + mv*16 + lr)*TT + kc*64 + kb*32 + g*8);
                #pragma unroll
                for (int nb = 0; nb < 2; ++nb) {
                    bf16x8 pf = *(const bf16x8*)&Pl[w][nb*16 + lr][kb*32 + g*8];
                    o[mv][nb] = MFMA_BF16(vf, pf, o[mv][nb], 0, 0, 0);
                }
            }
            #pragma unroll
            for (int nb = 0; nb < 2; ++nb) {
                bf16x8 pf = *(const bf16x8*)&Pl[w][nb*16 + lr][kb*32 + g*8];
                dacc[nb] = MFMA_BF16(ones, pf, dacc[nb], 0, 0, 0);
            }
        }
    }

    __syncthreads();   // all waves done with Pl (scratch overlays it)

    #pragma unroll
    for (int mv = 0; mv < 4; ++mv)
        #pragma unroll
        for (int nb = 0; nb < 2; ++nb)
            *(f32x4*)&scf[(size_t)(w*32 + nb*16 + lr)*68 + mv*16 + g*4] = o[mv][nb];
    if (g == 0) {
        scd[w*32 + lr]      = dacc[0][0];
        scd[w*32 + 16 + lr] = dacc[1][0];
    }

    __syncthreads();

    {
        const int q  = tid >> 4;           // 0..31
        const int v0 = (tid & 15) * 4;     // 0..60
        float dtot = 0.f;
        #pragma unroll
        for (int ww = 0; ww < 8; ++ww) dtot += scd[ww*32 + q];
        const float inv = 1.0f / (dtot + 1e-12f);
        float o0 = 0.f, o1 = 0.f, o2 = 0.f, o3 = 0.f;
        #pragma unroll
        for (int ww = 0; ww < 8; ++ww) {
            const float* p = &scf[(size_t)(ww*32 + q)*68 + v0];
            o0 += p[0]; o1 += p[1]; o2 += p[2]; o3 += p[3];
        }
        uint2 pk = { pkbf2(o0*inv, o1*inv), pkbf2(o2*inv, o3*inv) };
        *(uint2*)(Yb + ((size_t)(b*TT + qt*32 + q))*DD + h*HDIM + v0) = pk;
    }
}

// ---------------------------------------------------------------------------
// Kernel 3: output projection, bf16 MFMA, K-split 8-wave (round-21 body,
// unchanged).
// ---------------------------------------------------------------------------
__global__ __launch_bounds__(512) void out_mfma(
    const ushort* __restrict__ Yb, const ushort* __restrict__ Wob,
    float* __restrict__ Out)
{
    __shared__ float sc[2][64][66];
    const int m0 = blockIdx.x * 64, n0 = blockIdx.y * 64;
    const int tid = threadIdx.x, w = tid >> 6, l = tid & 63;
    const int kw = w >> 2, mw = w & 1, nw = (w >> 1) & 1;
    const int lr = l & 15, g = l >> 4;

    f32x4 acc[2][2] = {};
    const ushort* Ar = Yb  + (size_t)(m0 + mw*32 + lr) * 512 + kw*256 + g*8;
    const ushort* Br = Wob + (size_t)(n0 + nw*32 + lr) * 512 + kw*256 + g*8;

    bf16x8 a0c = *(const bf16x8*)(Ar);
    bf16x8 a1c = *(const bf16x8*)(Ar + (size_t)16*512);
    bf16x8 b0c = *(const bf16x8*)(Br);
    bf16x8 b1c = *(const bf16x8*)(Br + (size_t)16*512);
    #pragma unroll
    for (int ks = 0; ks < 8; ++ks) {
        bf16x8 a0n = a0c, a1n = a1c, b0n = b0c, b1n = b1c;
        if (ks < 7) {
            a0n = *(const bf16x8*)(Ar + (ks+1)*32);
            a1n = *(const bf16x8*)(Ar + (size_t)16*512 + (ks+1)*32);
            b0n = *(const bf16x8*)(Br + (ks+1)*32);
            b1n = *(const bf16x8*)(Br + (size_t)16*512 + (ks+1)*32);
        }
        acc[0][0] = MFMA_BF16(a0c, b0c, acc[0][0], 0, 0, 0);
        acc[0][1] = MFMA_BF16(a0c, b1c, acc[0][1], 0, 0, 0);
        acc[1][0] = MFMA_BF16(a1c, b0c, acc[1][0], 0, 0, 0);
        acc[1][1] = MFMA_BF16(a1c, b1c, acc[1][1], 0, 0, 0);
        a0c = a0n; a1c = a1n; b0c = b0n; b1c = b1n;
    }

    #pragma unroll
    for (int mb = 0; mb < 2; ++mb)
        #pragma unroll
        for (int nb = 0; nb < 2; ++nb)
            #pragma unroll
            for (int r = 0; r < 4; ++r)
                sc[kw][mw*32 + mb*16 + g*4 + r][nw*32 + nb*16 + lr] = acc[mb][nb][r];
    __syncthreads();

    const int vl = tid & 63, rg = tid >> 6;
    #pragma unroll
    for (int j = 0; j < 8; ++j) {
        const float v = sc[0][rg*8 + j][vl] + sc[1][rg*8 + j][vl];
        Out[(size_t)(m0 + rg*8 + j)*512 + n0 + vl] = v;
    }
}

// ---------------------------------------------------------------------------
extern "C" void kernel_launch(void* const* d_in, const int* in_sizes, int n_in,
                              void* d_out, int out_size, void* d_ws, size_t ws_size,
                              hipStream_t stream) {
    const float* X  = (const float*)d_in[0];   // (2,1024,512)
    const float* Wq = (const float*)d_in[1];   // (128,512)
    const float* Wk = (const float*)d_in[2];   // (128,512)
    const float* Wv = (const float*)d_in[3];   // (512,512)
    const float* Wo = (const float*)d_in[4];   // (512,512)
    float* out = (float*)d_out;                // (2,1024,512)

    ushort* ws = (ushort*)d_ws;
    ushort* Wob = ws;                    // 512*512    = 262144
    ushort* Qb  = Wob + 262144;          // 16*1024*16 = 262144
    ushort* Kb  = Qb  + 262144;          // 262144
    ushort* Vtg = Kb  + 262144;          // 16*64*1024 = 1048576
    ushort* Yb  = Vtg + 1048576;         // 2048*512   = 1048576
    // total 2,883,584 ushorts = 5.8 MB

    dim3 g1(16, 7);           // 16x6 fused cast+QKV tiles + 16x1 Wo-cast
    qkv_f32<<<g1, 512, 0, stream>>>(X, Wq, Wk, Wv, Wo, Qb, Kb, Vtg, Wob);

    attn_mfma<<<512, 512, 0, stream>>>(Qb, Kb, Vtg, Yb);

    dim3 g3(BT/64, DD/64);    // 32 x 8 = 256 blocks, 512 thr
    out_mfma<<<g3, 512, 0, stream>>>(Yb, Wob, out);
}